// Round 3
// baseline (130.090 us; speedup 1.0000x reference)
//
#include <hip/hip_runtime.h>
#include <hip/hip_cooperative_groups.h>

namespace cg = cooperative_groups;

// Problem constants (match reference)
#define NCONF   8
#define NATOMS  10
#define NSTATES 4
#define NBASIS  24
#define HIDDEN  48
#define NPAIRC  90          // ordered pairs per conf: 10*9
#define NNEI    9           // pairs per center atom
#define NDIR    30          // NATOMS*3 second-derivative directions
#define CUTOFF  6.0f
#define ALPHA   1.5f
#define PI_F    3.14159265358979323846f

// Second-order forward-mode jets (v, dv, d2v) per (conf, direction).
// kin[c,s] = -0.5 * sum_{m,l} massrev[c,m] * d2 psi[c,s] / d cart[c,m,l]^2
// == reference's einsum('jmliml->jmi') contracted with massrev.
//
// R3: single cooperative kernel — 240 blocks compute jet outputs into ws,
// grid.sync(), block 0 reduces to the scalar loss. Saves one graph dispatch
// + finish_kernel cold-start; one barrier phase merged (wred -> emit).

__device__ __forceinline__ float fast_tanh(float x) {
    return 1.0f - 2.0f / (__expf(2.0f * x) + 1.0f);
}

__global__ __launch_bounds__(256) void fused_kernel(
    const float* __restrict__ cart,      // [NCONF*NATOMS*3]
    const int*   __restrict__ species,   // [NCONF*NATOMS]
    const float* __restrict__ massrev,   // [NCONF*NATOMS]
    const int*   __restrict__ ai,        // [2*npairs]
    const float* __restrict__ shifts,    // [npairs*3]
    const float* __restrict__ W1,        // [NBASIS*HIDDEN]
    const float* __restrict__ B1,        // [NTYPES*HIDDEN]
    const float* __restrict__ W2,        // [HIDDEN*NSTATES]
    const float* __restrict__ Emb,       // [NTYPES*NSTATES]
    int npairs,
    float* __restrict__ ws,              // [NCONF*NDIR*NSTATES + NCONF*NSTATES]
    const float* __restrict__ pot,       // [NCONF]
    const float* __restrict__ elevel,    // [NSTATES]
    float* __restrict__ out)             // [1]
{
    __shared__ float cartc[NATOMS][3];
    __shared__ int   spec[NATOMS];
    __shared__ int   cnt[NATOMS];
    __shared__ int   plist[NATOMS][NNEI];
    __shared__ int   jdst[NPAIRC];
    __shared__ float pJ[NPAIRC][9];          // dv,dg,dh | fv,fg,fh | rv,rg,rh
    __shared__ float denJ[NATOMS][NBASIS][3];
    __shared__ float hJ[NATOMS][HIDDEN][3];
    __shared__ float psJ[NATOMS][NSTATES][3];
    __shared__ float W1s[NBASIS * HIDDEN];
    __shared__ float wred[4][NSTATES][3];

    const int tid = threadIdx.x;
    const int c   = blockIdx.x / NDIR;
    const int d   = blockIdx.x % NDIR;
    const int m   = d / 3, l = d % 3;

    if (tid < NATOMS*3) cartc[tid/3][tid%3] = cart[c*NATOMS*3 + tid];
    if (tid < NATOMS)   { spec[tid] = species[c*NATOMS + tid]; cnt[tid] = 0; }
    for (int t = tid; t < NBASIS*HIDDEN; t += 256) W1s[t] = W1[t];
    __syncthreads();

    const float kc = PI_F / CUTOFF;

    // ---- per-pair jets: dist, fcut, radial; build per-atom pair lists ----
    if (tid < NPAIRC) {
        const int p  = tid;
        const int pg = c*NPAIRC + p;
        const int i = ai[pg]          - c*NATOMS;
        const int j = ai[npairs + pg] - c*NATOMS;
        const int k = atomicAdd(&cnt[i], 1);
        plist[i][k] = p;
        jdst[p] = j;
        const float sg = (float)((j == m) - (i == m));   // d dvec[l] / d eps
        const float dv0 = cartc[j][0] + shifts[pg*3+0] - cartc[i][0];
        const float dv1 = cartc[j][1] + shifts[pg*3+1] - cartc[i][1];
        const float dv2 = cartc[j][2] + shifts[pg*3+2] - cartc[i][2];
        const float dvl = (l == 0) ? dv0 : (l == 1) ? dv1 : dv2;
        const float r2v = dv0*dv0 + dv1*dv1 + dv2*dv2;
        const float r2g = 2.f*dvl*sg;
        const float r2h = 2.f*sg*sg;
        // dist = sqrt(r2)
        const float dvv = __fsqrt_rn(r2v);
        const float inv = 0.5f / dvv;
        const float dg  = r2g * inv;
        const float dh  = r2h * inv - 0.25f * r2g * r2g / (r2v * dvv);
        // radial = sin(kc*dist)^3 on UNclamped dist
        const float u  = kc * dvv;
        const float su = __sinf(u), cu = __cosf(u);
        const float r1  = 3.f*su*su*cu*kc;
        const float r2d = kc*kc*(6.f*su*cu*cu - 3.f*su*su*su);
        // fcut on clamped dist
        float dcv, dcg, dch;
        if (dvv < CUTOFF) { dcv = dvv; dcg = dg; dch = dh; }
        else              { dcv = CUTOFF; dcg = 0.f; dch = 0.f; }
        const float uc = kc * dcv;
        const float fv = 0.5f*(__cosf(uc) + 1.f);
        const float f1 = -0.5f*kc*__sinf(uc);
        const float f2 = -0.5f*kc*kc*__cosf(uc);
        pJ[p][0] = dvv; pJ[p][1] = dg;            pJ[p][2] = dh;
        pJ[p][3] = fv;  pJ[p][4] = f1*dcg;        pJ[p][5] = f1*dch + f2*dcg*dcg;
        pJ[p][6] = su*su*su;
        pJ[p][7] = r1*dg;
        pJ[p][8] = r1*dh + r2d*dg*dg;
    }
    __syncthreads();

    // ---- density jets: per (a,b), direct 9-pair loop, gaussians on the fly ----
    if (tid < NATOMS*NBASIS) {
        const int a = tid / NBASIS, b = tid % NBASIS;
        const float cb = (CUTOFF/23.0f) * (float)b;
        float s0 = 0.f, s1 = 0.f, s2 = 0.f;
        #pragma unroll
        for (int k = 0; k < NNEI; ++k) {
            const int p = plist[a][k];
            const float dvv = pJ[p][0], dg = pJ[p][1], dh = pJ[p][2];
            const float fv  = pJ[p][3], fg = pJ[p][4], fh = pJ[p][5];
            const float t  = dvv - cb;
            const float ev = __expf(-ALPHA*t*t);
            const float e1 = -2.f*ALPHA*t*ev;
            const float e2 = (-2.f*ALPHA + 4.f*ALPHA*ALPHA*t*t)*ev;
            const float eg = e1*dg;
            const float eh = e1*dh + e2*dg*dg;
            s0 += ev*fv;
            s1 += ev*fg + eg*fv;
            s2 += ev*fh + 2.f*eg*fg + eh*fv;
        }
        denJ[a][b][0] = s0; denJ[a][b][1] = s1; denJ[a][b][2] = s2;
    }
    __syncthreads();

    // ---- hidden = tanh(density @ W1 + B1[spec]) : 480 tasks ----
    for (int task = tid; task < NATOMS*HIDDEN; task += 256) {
        const int a = task / HIDDEN, hd = task % HIDDEN;
        float v = B1[spec[a]*HIDDEN + hd], g = 0.f, hh = 0.f;
        #pragma unroll
        for (int b = 0; b < NBASIS; ++b) {
            const float w = W1s[b*HIDDEN + hd];
            v  += denJ[a][b][0]*w;
            g  += denJ[a][b][1]*w;
            hh += denJ[a][b][2]*w;
        }
        const float y  = fast_tanh(v);
        const float y1 = 1.f - y*y;
        hJ[a][hd][0] = y;
        hJ[a][hd][1] = y1*g;
        hJ[a][hd][2] = y1*hh - 2.f*y*y1*g*g;
    }
    __syncthreads();

    // ---- initpsi = h @ W2 + Emb[spec] : 40 tasks ----
    if (tid < NATOMS*NSTATES) {
        const int a = tid / NSTATES, s = tid % NSTATES;
        float v = Emb[spec[a]*NSTATES + s], g = 0.f, hh = 0.f;
        #pragma unroll
        for (int hd = 0; hd < HIDDEN; ++hd) {
            const float w = W2[hd*NSTATES + s];
            v  += hJ[a][hd][0]*w;
            g  += hJ[a][hd][1]*w;
            hh += hJ[a][hd][2]*w;
        }
        psJ[a][s][0] = v; psJ[a][s][1] = g; psJ[a][s][2] = hh;
    }
    __syncthreads();

    // ---- tmppsi[s] = sum_p initpsi[jdst[p]] * radial[p] (jet product) ----
    float acc[NSTATES][3];
    #pragma unroll
    for (int s = 0; s < NSTATES; ++s) acc[s][0] = acc[s][1] = acc[s][2] = 0.f;
    if (tid < NPAIRC) {
        const int p = tid;
        const int j = jdst[p];
        const float rv = pJ[p][6], rg = pJ[p][7], rh = pJ[p][8];
        #pragma unroll
        for (int s = 0; s < NSTATES; ++s) {
            const float iv = psJ[j][s][0], ig = psJ[j][s][1], ih = psJ[j][s][2];
            acc[s][0] += iv*rv;
            acc[s][1] += iv*rg + ig*rv;
            acc[s][2] += iv*rh + 2.f*ig*rg + ih*rv;
        }
    }
    #pragma unroll
    for (int off = 32; off > 0; off >>= 1)
        #pragma unroll
        for (int s = 0; s < NSTATES; ++s)
            #pragma unroll
            for (int k = 0; k < 3; ++k)
                acc[s][k] += __shfl_down(acc[s][k], off, 64);
    if ((tid & 63) == 0)
        #pragma unroll
        for (int s = 0; s < NSTATES; ++s)
            #pragma unroll
            for (int k = 0; k < 3; ++k) wred[tid >> 6][s][k] = acc[s][k];
    __syncthreads();

    // ---- psi (square on state 0); emit massrev-weighted psi'' and psi ----
    if (tid < NSTATES) {
        const int s = tid;
        float t = 0.f, g = 0.f, hh = 0.f;
        #pragma unroll
        for (int w = 0; w < 4; ++w) {
            t  += wred[w][s][0];
            g  += wred[w][s][1];
            hh += wred[w][s][2];
        }
        float pv, ph;
        if (s == 0) { pv = t*t; ph = 2.f*(t*hh + g*g); }
        else        { pv = t;   ph = hh; }
        ws[(c*NDIR + d)*NSTATES + s] = massrev[c*NATOMS + m] * ph;
        if (d == 0) ws[NCONF*NDIR*NSTATES + c*NSTATES + s] = pv;
    }

    // ---- grid-wide barrier, then block 0 computes the scalar loss ----
    cg::this_grid().sync();

    if (blockIdx.x == 0 && tid < 64) {
        float val = 0.f;
        if (tid < NCONF*NSTATES) {
            const int cc = tid / NSTATES, s = tid % NSTATES;
            float kin = 0.f;
            #pragma unroll
            for (int dd = 0; dd < NDIR; ++dd) kin += ws[(cc*NDIR + dd)*NSTATES + s];
            kin *= -0.5f;                              // FACTOR_KIN with the minus sign
            const float psi    = ws[NCONF*NDIR*NSTATES + cc*NSTATES + s];
            const float potene = pot[cc] - pot[NCONF-1];
            const float vib    = (kin + psi*potene) / psi;
            const float e      = vib - elevel[s];
            val = e*e;
        }
        #pragma unroll
        for (int off = 32; off > 0; off >>= 1) val += __shfl_down(val, off, 64);
        if (tid == 0) out[0] = val;
    }
}

extern "C" void kernel_launch(void* const* d_in, const int* in_sizes, int n_in,
                              void* d_out, int out_size, void* d_ws, size_t ws_size,
                              hipStream_t stream) {
    // input order: eigen_weight, pot, cart, numatoms, species, massrev,
    //              atom_index, shifts, W1, B1, W2, Emb, elevel
    const float* pot     = (const float*)d_in[1];
    const float* cart    = (const float*)d_in[2];
    const int*   species = (const int*)  d_in[4];
    const float* massrev = (const float*)d_in[5];
    const int*   ai      = (const int*)  d_in[6];
    const float* shifts  = (const float*)d_in[7];
    const float* W1      = (const float*)d_in[8];
    const float* B1      = (const float*)d_in[9];
    const float* W2      = (const float*)d_in[10];
    const float* Emb     = (const float*)d_in[11];
    const float* elevel  = (const float*)d_in[12];
    int npairs = in_sizes[6] / 2;

    float* ws  = (float*)d_ws;   // 992 floats used
    float* out = (float*)d_out;

    void* args[] = {
        (void*)&cart, (void*)&species, (void*)&massrev, (void*)&ai, (void*)&shifts,
        (void*)&W1, (void*)&B1, (void*)&W2, (void*)&Emb, (void*)&npairs,
        (void*)&ws, (void*)&pot, (void*)&elevel, (void*)&out
    };
    hipLaunchCooperativeKernel((void*)fused_kernel, dim3(NCONF*NDIR), dim3(256),
                               args, 0, stream);
}

// Round 4
// 84.048 us; speedup vs baseline: 1.5478x; 1.5478x over previous
//
#include <hip/hip_runtime.h>

// Problem constants (match reference)
#define NCONF   8
#define NATOMS  10
#define NSTATES 4
#define NBASIS  24
#define HIDDEN  48
#define NPAIRC  90          // ordered pairs per conf: 10*9
#define NNEI    9           // pairs per center atom (and per destination atom)
#define NDIR    30          // NATOMS*3 second-derivative directions
#define CUTOFF  6.0f
#define ALPHA   1.5f
#define PI_F    3.14159265358979323846f

// Second-order forward-mode jets (v, dv, d2v) per (conf, direction).
// kin[c,s] = -0.5 * sum_{m,l} massrev[c,m] * d2 psi[c,s] / d cart[c,m,l]^2
// == reference's einsum('jmliml->jmi') contracted with massrev.
//
// R4: revert cooperative launch (R3: +43us regression — coop dispatch path is
// far slower than two graph-replayed dispatches). Keep R2 structure; cut the
// critical path further: destination-grouped radial sums R_j (computed by 10
// spare threads overlapped with the density phase) turn the 90-pair product +
// 6-stage shuffle chain + wred LDS round-trip into a 4-thread x 10-atom loop.
// tmppsi[s] = sum_j R_j (x) initpsi[j,s]   (jet product is bilinear).

__device__ __forceinline__ float fast_tanh(float x) {
    return 1.0f - 2.0f / (__expf(2.0f * x) + 1.0f);
}

__global__ __launch_bounds__(256) void jet_kernel(
    const float* __restrict__ cart,      // [NCONF*NATOMS*3]
    const int*   __restrict__ species,   // [NCONF*NATOMS]
    const float* __restrict__ massrev,   // [NCONF*NATOMS]
    const int*   __restrict__ ai,        // [2*npairs]
    const float* __restrict__ shifts,    // [npairs*3]
    const float* __restrict__ W1,        // [NBASIS*HIDDEN]
    const float* __restrict__ B1,        // [NTYPES*HIDDEN]
    const float* __restrict__ W2,        // [HIDDEN*NSTATES]
    const float* __restrict__ Emb,       // [NTYPES*NSTATES]
    int npairs,
    float* __restrict__ ws)              // [NCONF*NDIR*NSTATES + NCONF*NSTATES]
{
    __shared__ float cartc[NATOMS][3];
    __shared__ int   spec[NATOMS];
    __shared__ int   cnt[NATOMS], dcnt[NATOMS];
    __shared__ int   plist[NATOMS][NNEI];    // pairs by center (source) atom
    __shared__ int   dlist[NATOMS][NNEI];    // pairs by destination atom
    __shared__ float pJ[NPAIRC][9];          // dv,dg,dh | fv,fg,fh | rv,rg,rh
    __shared__ float RJ[NATOMS][3];          // sum of radial jets by destination
    __shared__ float denJ[NATOMS][NBASIS][3];
    __shared__ float hJ[NATOMS][HIDDEN][3];
    __shared__ float psJ[NATOMS][NSTATES][3];
    __shared__ float W1s[NBASIS * HIDDEN];

    const int tid = threadIdx.x;
    const int c   = blockIdx.x / NDIR;
    const int d   = blockIdx.x % NDIR;
    const int m   = d / 3, l = d % 3;

    if (tid < NATOMS*3) cartc[tid/3][tid%3] = cart[c*NATOMS*3 + tid];
    if (tid < NATOMS)   { spec[tid] = species[c*NATOMS + tid]; cnt[tid] = 0; dcnt[tid] = 0; }
    for (int t = tid; t < NBASIS*HIDDEN; t += 256) W1s[t] = W1[t];
    __syncthreads();

    const float kc = PI_F / CUTOFF;

    // ---- per-pair jets: dist, fcut, radial; build src- and dst-grouped lists ----
    if (tid < NPAIRC) {
        const int p  = tid;
        const int pg = c*NPAIRC + p;
        const int i = ai[pg]          - c*NATOMS;
        const int j = ai[npairs + pg] - c*NATOMS;
        plist[i][atomicAdd(&cnt[i], 1)]  = p;
        dlist[j][atomicAdd(&dcnt[j], 1)] = p;
        const float sg = (float)((j == m) - (i == m));   // d dvec[l] / d eps
        const float dv0 = cartc[j][0] + shifts[pg*3+0] - cartc[i][0];
        const float dv1 = cartc[j][1] + shifts[pg*3+1] - cartc[i][1];
        const float dv2 = cartc[j][2] + shifts[pg*3+2] - cartc[i][2];
        const float dvl = (l == 0) ? dv0 : (l == 1) ? dv1 : dv2;
        const float r2v = dv0*dv0 + dv1*dv1 + dv2*dv2;
        const float r2g = 2.f*dvl*sg;
        const float r2h = 2.f*sg*sg;
        // dist = sqrt(r2)
        const float dvv = __fsqrt_rn(r2v);
        const float inv = 0.5f / dvv;
        const float dg  = r2g * inv;
        const float dh  = r2h * inv - 0.25f * r2g * r2g / (r2v * dvv);
        // radial = sin(kc*dist)^3 on UNclamped dist
        const float u  = kc * dvv;
        const float su = __sinf(u), cu = __cosf(u);
        const float r1  = 3.f*su*su*cu*kc;
        const float r2d = kc*kc*(6.f*su*cu*cu - 3.f*su*su*su);
        // fcut on clamped dist
        float dcv, dcg, dch;
        if (dvv < CUTOFF) { dcv = dvv; dcg = dg; dch = dh; }
        else              { dcv = CUTOFF; dcg = 0.f; dch = 0.f; }
        const float uc = kc * dcv;
        const float fv = 0.5f*(__cosf(uc) + 1.f);
        const float f1 = -0.5f*kc*__sinf(uc);
        const float f2 = -0.5f*kc*kc*__cosf(uc);
        pJ[p][0] = dvv; pJ[p][1] = dg;            pJ[p][2] = dh;
        pJ[p][3] = fv;  pJ[p][4] = f1*dcg;        pJ[p][5] = f1*dch + f2*dcg*dcg;
        pJ[p][6] = su*su*su;
        pJ[p][7] = r1*dg;
        pJ[p][8] = r1*dh + r2d*dg*dg;
    }
    __syncthreads();

    // ---- density jets (threads 0..239) + dst-grouped radial sums (240..249) ----
    if (tid < NATOMS*NBASIS) {
        const int a = tid / NBASIS, b = tid % NBASIS;
        const float cb = (CUTOFF/23.0f) * (float)b;
        float s0 = 0.f, s1 = 0.f, s2 = 0.f;
        #pragma unroll
        for (int k = 0; k < NNEI; ++k) {
            const int p = plist[a][k];
            const float dvv = pJ[p][0], dg = pJ[p][1], dh = pJ[p][2];
            const float fv  = pJ[p][3], fg = pJ[p][4], fh = pJ[p][5];
            const float t  = dvv - cb;
            const float ev = __expf(-ALPHA*t*t);
            const float e1 = -2.f*ALPHA*t*ev;
            const float e2 = (-2.f*ALPHA + 4.f*ALPHA*ALPHA*t*t)*ev;
            const float eg = e1*dg;
            const float eh = e1*dh + e2*dg*dg;
            s0 += ev*fv;
            s1 += ev*fg + eg*fv;
            s2 += ev*fh + 2.f*eg*fg + eh*fv;
        }
        denJ[a][b][0] = s0; denJ[a][b][1] = s1; denJ[a][b][2] = s2;
    } else if (tid < NATOMS*NBASIS + NATOMS) {
        const int j = tid - NATOMS*NBASIS;
        float r0 = 0.f, r1 = 0.f, r2 = 0.f;
        #pragma unroll
        for (int k = 0; k < NNEI; ++k) {
            const int p = dlist[j][k];
            r0 += pJ[p][6]; r1 += pJ[p][7]; r2 += pJ[p][8];
        }
        RJ[j][0] = r0; RJ[j][1] = r1; RJ[j][2] = r2;
    }
    __syncthreads();

    // ---- hidden = tanh(density @ W1 + B1[spec]) : 480 tasks ----
    for (int task = tid; task < NATOMS*HIDDEN; task += 256) {
        const int a = task / HIDDEN, hd = task % HIDDEN;
        float v = B1[spec[a]*HIDDEN + hd], g = 0.f, hh = 0.f;
        #pragma unroll
        for (int b = 0; b < NBASIS; ++b) {
            const float w = W1s[b*HIDDEN + hd];
            v  += denJ[a][b][0]*w;
            g  += denJ[a][b][1]*w;
            hh += denJ[a][b][2]*w;
        }
        const float y  = fast_tanh(v);
        const float y1 = 1.f - y*y;
        hJ[a][hd][0] = y;
        hJ[a][hd][1] = y1*g;
        hJ[a][hd][2] = y1*hh - 2.f*y*y1*g*g;
    }
    __syncthreads();

    // ---- initpsi = h @ W2 + Emb[spec] : 40 tasks ----
    if (tid < NATOMS*NSTATES) {
        const int a = tid / NSTATES, s = tid % NSTATES;
        float v = Emb[spec[a]*NSTATES + s], g = 0.f, hh = 0.f;
        #pragma unroll
        for (int hd = 0; hd < HIDDEN; ++hd) {
            const float w = W2[hd*NSTATES + s];
            v  += hJ[a][hd][0]*w;
            g  += hJ[a][hd][1]*w;
            hh += hJ[a][hd][2]*w;
        }
        psJ[a][s][0] = v; psJ[a][s][1] = g; psJ[a][s][2] = hh;
    }
    __syncthreads();

    // ---- tmppsi[s] = sum_j RJ[j] (x) initpsi[j,s]; psi; emit ----
    if (tid < NSTATES) {
        const int s = tid;
        float t = 0.f, g = 0.f, hh = 0.f;
        #pragma unroll
        for (int j = 0; j < NATOMS; ++j) {
            const float rv = RJ[j][0], rg = RJ[j][1], rh = RJ[j][2];
            const float iv = psJ[j][s][0], ig = psJ[j][s][1], ih = psJ[j][s][2];
            t  += iv*rv;
            g  += iv*rg + ig*rv;
            hh += iv*rh + 2.f*ig*rg + ih*rv;
        }
        float pv, ph;
        if (s == 0) { pv = t*t; ph = 2.f*(t*hh + g*g); }
        else        { pv = t;   ph = hh; }
        ws[(c*NDIR + d)*NSTATES + s] = massrev[c*NATOMS + m] * ph;
        if (d == 0) ws[NCONF*NDIR*NSTATES + c*NSTATES + s] = pv;
    }
}

__global__ __launch_bounds__(64) void finish_kernel(
    const float* __restrict__ ws,
    const float* __restrict__ pot,
    const float* __restrict__ elevel,
    float* __restrict__ out)
{
    const int t = threadIdx.x;
    float val = 0.f;
    if (t < NCONF*NSTATES) {
        const int c = t / NSTATES, s = t % NSTATES;
        float kin = 0.f;
        #pragma unroll
        for (int d = 0; d < NDIR; ++d) kin += ws[(c*NDIR + d)*NSTATES + s];
        kin *= -0.5f;                                  // FACTOR_KIN with the minus sign
        const float psi    = ws[NCONF*NDIR*NSTATES + c*NSTATES + s];
        const float potene = pot[c] - pot[NCONF-1];
        const float vib    = (kin + psi*potene) / psi;
        const float e      = vib - elevel[s];
        val = e*e;
    }
    #pragma unroll
    for (int off = 32; off > 0; off >>= 1) val += __shfl_down(val, off, 64);
    if (t == 0) out[0] = val;
}

extern "C" void kernel_launch(void* const* d_in, const int* in_sizes, int n_in,
                              void* d_out, int out_size, void* d_ws, size_t ws_size,
                              hipStream_t stream) {
    // input order: eigen_weight, pot, cart, numatoms, species, massrev,
    //              atom_index, shifts, W1, B1, W2, Emb, elevel
    const float* pot     = (const float*)d_in[1];
    const float* cart    = (const float*)d_in[2];
    const int*   species = (const int*)  d_in[4];
    const float* massrev = (const float*)d_in[5];
    const int*   ai      = (const int*)  d_in[6];
    const float* shifts  = (const float*)d_in[7];
    const float* W1      = (const float*)d_in[8];
    const float* B1      = (const float*)d_in[9];
    const float* W2      = (const float*)d_in[10];
    const float* Emb     = (const float*)d_in[11];
    const float* elevel  = (const float*)d_in[12];
    const int npairs = in_sizes[6] / 2;

    float* ws = (float*)d_ws;   // 992 floats used

    jet_kernel<<<NCONF*NDIR, 256, 0, stream>>>(cart, species, massrev, ai, shifts,
                                               W1, B1, W2, Emb, npairs, ws);
    finish_kernel<<<1, 64, 0, stream>>>(ws, pot, elevel, (float*)d_out);
}